// Round 6
// baseline (305.570 us; speedup 1.0000x reference)
//
#include <hip/hip_runtime.h>
#include <hip/hip_bf16.h>

// Problem constants
#define VOCAB 50000
#define ED    300
#define NT    16
#define BB    64
#define SS    512

#define LOG2E 1.4426950408889634f
#define LN2   0.6931471805599453f
#define WSTR  308   // padded W-transpose stride (2-way bank aliasing = free)

// ---------------------------------------------------------------------------
// Tiny init: zero the 64 per-batch producer counters in d_ws (poison-proof).
// ---------------------------------------------------------------------------
__global__ __launch_bounds__(64) void init_flags(unsigned int* __restrict__ f) {
  f[threadIdx.x] = 0u;
}

// ---------------------------------------------------------------------------
// DPP helpers (controls HW-verified rounds 1-5). old = src (involutions, all
// lanes active -> old never observed).
// ---------------------------------------------------------------------------
template <int CTRL>
__device__ __forceinline__ float dppmov(float x) {
  int xi = __float_as_int(x);
  return __int_as_float(
      __builtin_amdgcn_update_dpp(xi, xi, CTRL, 0xF, 0xF, false));
}

// ---------------------------------------------------------------------------
// One CRF forward step, fused DPP matvec (HW-verified rounds 3-5).
//   gn_j = (sum_k alpha_{j^k} * E[k]_j) * pe_j,  E[k]_j = exp(trans[j^k, j])
// ---------------------------------------------------------------------------
__device__ __forceinline__ float crf_step(float g, float pe, const float E[16]) {
  float gn, h, m, c, a1, a2, a3;
  asm("s_nop 1\n\t"
      "v_mov_b32_dpp %[h], %[g] row_half_mirror row_mask:0xf bank_mask:0xf\n\t"
      "v_mov_b32_dpp %[m], %[g] row_mirror row_mask:0xf bank_mask:0xf\n\t"
      "v_mul_f32 %[gn], %[g], %[e0]\n\t"
      "v_fmac_f32_dpp %[gn], %[g], %[e1] quad_perm:[1,0,3,2] row_mask:0xf bank_mask:0xf\n\t"
      "v_fmac_f32_dpp %[gn], %[g], %[e2] quad_perm:[2,3,0,1] row_mask:0xf bank_mask:0xf\n\t"
      "v_fmac_f32_dpp %[gn], %[g], %[e3] quad_perm:[3,2,1,0] row_mask:0xf bank_mask:0xf\n\t"
      "v_mov_b32_dpp %[c], %[m] row_half_mirror row_mask:0xf bank_mask:0xf\n\t"
      "v_mul_f32 %[a1], %[h], %[e7]\n\t"
      "v_fmac_f32_dpp %[a1], %[h], %[e6] quad_perm:[1,0,3,2] row_mask:0xf bank_mask:0xf\n\t"
      "v_fmac_f32_dpp %[a1], %[h], %[e5] quad_perm:[2,3,0,1] row_mask:0xf bank_mask:0xf\n\t"
      "v_fmac_f32_dpp %[a1], %[h], %[e4] quad_perm:[3,2,1,0] row_mask:0xf bank_mask:0xf\n\t"
      "v_mul_f32 %[a2], %[m], %[e15]\n\t"
      "v_fmac_f32_dpp %[a2], %[m], %[e14] quad_perm:[1,0,3,2] row_mask:0xf bank_mask:0xf\n\t"
      "v_fmac_f32_dpp %[a2], %[m], %[e13] quad_perm:[2,3,0,1] row_mask:0xf bank_mask:0xf\n\t"
      "v_fmac_f32_dpp %[a2], %[m], %[e12] quad_perm:[3,2,1,0] row_mask:0xf bank_mask:0xf\n\t"
      "v_mul_f32 %[a3], %[c], %[e8]\n\t"
      "v_fmac_f32_dpp %[a3], %[c], %[e9] quad_perm:[1,0,3,2] row_mask:0xf bank_mask:0xf\n\t"
      "v_fmac_f32_dpp %[a3], %[c], %[e10] quad_perm:[2,3,0,1] row_mask:0xf bank_mask:0xf\n\t"
      "v_fmac_f32_dpp %[a3], %[c], %[e11] quad_perm:[3,2,1,0] row_mask:0xf bank_mask:0xf\n\t"
      "v_add_f32 %[gn], %[gn], %[a1]\n\t"
      "v_add_f32 %[a2], %[a2], %[a3]\n\t"
      "v_add_f32 %[gn], %[gn], %[a2]\n\t"
      "v_mul_f32 %[gn], %[gn], %[pe]"
      : [gn] "=&v"(gn), [h] "=&v"(h), [m] "=&v"(m), [c] "=&v"(c),
        [a1] "=&v"(a1), [a2] "=&v"(a2), [a3] "=&v"(a3)
      : [g] "v"(g), [pe] "v"(pe),
        [e0] "v"(E[0]), [e1] "v"(E[1]), [e2] "v"(E[2]), [e3] "v"(E[3]),
        [e4] "v"(E[4]), [e5] "v"(E[5]), [e6] "v"(E[6]), [e7] "v"(E[7]),
        [e8] "v"(E[8]), [e9] "v"(E[9]), [e10] "v"(E[10]), [e11] "v"(E[11]),
        [e12] "v"(E[12]), [e13] "v"(E[13]), [e14] "v"(E[14]), [e15] "v"(E[15]));
  return gn;
}

// ---------------------------------------------------------------------------
// Main kernel: 2048 blocks x 256 threads (round-4 probs structure).
// Part 1 (every block): probs rows [16*blk, 16*blk+16). W transposed in LDS;
//   vmcnt queue holds only e-loads; 8-deep rolling register prefetch.
// Then: __syncthreads (drains stores) + device-scope release add on
//   flags[batch]. Per-batch producer count = 32 blocks.
// Part 2 (wave 0 of block 32b only): acquire-spin for flags[b]==32, then
//   lens + phase A + the serial DPP scan, reading probs DIRECTLY from global
//   (16-step chunk prefetch ~544 cyc lookahead covers L2 latency). No LDS in
//   this phase -> kernel LDS stays 20 KB (W), preserving gather occupancy.
// Deadlock-free: runner 32b waits only on blocks 32b..32b+31 (which wait on
// nobody); non-runner blocks retire and free slots.
// ---------------------------------------------------------------------------
__global__ __launch_bounds__(256, 6) void main_kernel(
    const int* __restrict__ text, const int* __restrict__ tags,
    const float* __restrict__ emb, const float* __restrict__ W,
    const float* __restrict__ bias, const float* __restrict__ trans,
    float* __restrict__ out_probs, float* __restrict__ out_lens,
    float* __restrict__ out_ll, unsigned int* __restrict__ flags) {
  __shared__ float wt[NT * WSTR];  // 19.7 KB

  const int tid = threadIdx.x;
  const int lane = tid & 63, wave = tid >> 6;
  const int r = lane >> 4, t = lane & 15;
  const int row = blockIdx.x * 16 + wave * 4 + r;
  const int b = blockIdx.x >> 5;  // 32 blocks per batch

  // ---- part 1: stage W transposed (2-way write aliasing = free) ----
  for (int e = tid; e < ED * NT; e += 256) {
    int d = e >> 4, tt = e & 15;
    wt[tt * WSTR + d] = W[e];
  }

  const int tok = text[row];
  const float4* erow = (const float4*)(emb + (size_t)tok * ED);
  float acc = bias[t];

  float4 A[8];
#pragma unroll
  for (int i = 0; i < 8; ++i) A[i] = erow[i];

  __syncthreads();  // wt ready

  const float4* w4 = (const float4*)(wt + t * WSTR);
#pragma unroll
  for (int c = 0; c < 75; ++c) {
    float4 e = A[c & 7];
    if (c < 67) A[c & 7] = erow[c + 8];
    float4 w = w4[c];
    acc = fmaf(e.x, w.x, acc);
    acc = fmaf(e.y, w.y, acc);
    acc = fmaf(e.z, w.z, acc);
    acc = fmaf(e.w, w.w, acc);
  }
  out_probs[(size_t)row * NT + t] = acc;

  // publish: barrier drains this block's stores to L2, release-add flushes
  // device-visibly (cross-XCD per G16).
  __syncthreads();
  if (tid == 0) {
    __threadfence();
    __hip_atomic_fetch_add(&flags[b], 1u, __ATOMIC_RELEASE,
                           __HIP_MEMORY_SCOPE_AGENT);
  }

  if ((blockIdx.x & 31) != 0 || wave != 0) return;

  // ---- part 2: runner wave for batch b ----
  while (__hip_atomic_load(&flags[b], __ATOMIC_ACQUIRE,
                           __HIP_MEMORY_SCOPE_AGENT) != 32u)
    __builtin_amdgcn_s_sleep(2);
  __threadfence();

  const float* pb = out_probs + (size_t)b * SS * NT;
  const int* tg = tags + b * SS;
  const int* tx = text + b * SS;

  // lens
  int cnt = 0;
#pragma unroll
  for (int k = 0; k < 8; ++k) cnt += (tx[lane + 64 * k] != 0) ? 1 : 0;
  for (int off = 32; off > 0; off >>= 1) cnt += __shfl_xor(cnt, off, 64);
  const int len = cnt;
  if (lane == 0) out_lens[b] = (float)len;

  // phase A: unary + binary scores (global gathers; independent loads)
  float su = 0.f, sbin = 0.f;
#pragma unroll
  for (int it = 0; it < 8; ++it) {
    const int s = lane + 64 * it;
    if (s < len) {
      int t1 = tg[s];
      su += pb[s * NT + t1];
      if (s >= 1) sbin += trans[tg[s - 1] * 16 + t1];
    }
  }
  float sc = su + sbin;
  for (int off = 32; off > 0; off >>= 1) sc += __shfl_xor(sc, off, 64);

  // E[k] = exp(trans[j^k, j]), j = lane&15 (one-time gather; trans L1-hot)
  const int j = lane & 15;
  float E[16];
#pragma unroll
  for (int k = 0; k < 16; ++k) E[k] = __expf(trans[((j ^ k) << 4) + j]);

  // scan: s = 1 .. len-1 (steps s>=len are exact no-ops; skipped)
  float g = exp2f(pb[j] * LOG2E);
  float K2 = 0.f;

  const int T = (len > 0) ? len - 1 : 0;
  const int nfull = T >> 4;
  const int rem = T & 15;

  float raw[16];
#pragma unroll
  for (int c = 0; c < 16; ++c) raw[c] = pb[(1 + c) * NT + j];

  int s0 = 1;
  for (int blk = 0; blk < nfull; ++blk) {
#pragma unroll
    for (int c = 0; c < 16; ++c) {
      float pe = exp2f(raw[c] * LOG2E);
      // prefetch next chunk (row <= 512; may read past batch -> in d_out,
      // values unused)
      raw[c] = pb[(s0 + 16 + c) * NT + j];
      g = crf_step(g, pe, E);
    }
    // renorm every 16 steps (growth <= 2^90 < 2^127); exact fold into K2
    float mx = g;
    mx = fmaxf(mx, dppmov<0xB1>(mx));
    mx = fmaxf(mx, dppmov<0x4E>(mx));
    mx = fmaxf(mx, dppmov<0x141>(mx));
    mx = fmaxf(mx, dppmov<0x140>(mx));
    float rr = 1.0f / mx;
    K2 -= __log2f(rr);
    g *= rr;
    s0 += 16;
  }
  for (int c = 0; c < rem; ++c) {
    float pe = exp2f(raw[c] * LOG2E);
    g = crf_step(g, pe, E);
  }

  // final logsumexp across the 16 alphas
  float x = g;
  x += dppmov<0xB1>(x);
  x += dppmov<0x4E>(x);
  x += dppmov<0x141>(x);
  x += dppmov<0x140>(x);
  float log_norm = LN2 * (K2 + __log2f(x));
  if (lane == 0) out_ll[b] = sc - log_norm;
}

// ---------------------------------------------------------------------------
extern "C" void kernel_launch(void* const* d_in, const int* in_sizes, int n_in,
                              void* d_out, int out_size, void* d_ws, size_t ws_size,
                              hipStream_t stream) {
  const int* text = (const int*)d_in[0];
  const int* tags = (const int*)d_in[1];
  const float* emb = (const float*)d_in[2];
  const float* W = (const float*)d_in[3];
  const float* bias = (const float*)d_in[4];
  const float* trans = (const float*)d_in[5];

  float* out = (float*)d_out;
  float* out_probs = out;                   // 64*512*16
  float* out_lens = out + BB * SS * NT;     // 64
  float* out_ll = out + BB * SS * NT + BB;  // 64
  unsigned int* flags = (unsigned int*)d_ws;

  init_flags<<<1, 64, 0, stream>>>(flags);
  main_kernel<<<(BB * SS) / 16, 256, 0, stream>>>(
      text, tags, emb, W, bias, trans, out_probs, out_lens, out_ll, flags);
}

// Round 7
// 151.205 us; speedup vs baseline: 2.0209x; 2.0209x over previous
//
#include <hip/hip_runtime.h>
#include <hip/hip_bf16.h>

// Problem constants
#define VOCAB 50000
#define ED    300
#define NT    16
#define BB    64
#define SS    512

#define LOG2E 1.4426950408889634f
#define LN2   0.6931471805599453f
#define WSTR  308   // padded W-transpose stride (2-way bank aliasing = free)

// ---------------------------------------------------------------------------
// Kernel 1: probs[row,:] = emb[text[row]] @ W + bias.  (round-4 verified)
// Lane layout: r = lane>>4 (4 rows/wave), t = lane&15 (16 tags).
// W transposed in LDS; vmcnt queue holds ONLY e-loads; 8-deep rolling
// register prefetch covers the ~900cyc HBM-miss latency of the emb gather.
// ---------------------------------------------------------------------------
__global__ __launch_bounds__(256) void probs_kernel(const int* __restrict__ text,
                                                    const float* __restrict__ emb,
                                                    const float* __restrict__ W,
                                                    const float* __restrict__ bias,
                                                    float* __restrict__ out_probs) {
  __shared__ float wt[NT * WSTR];  // wt[t*WSTR + d] = W[d*16 + t]

  const int tid = threadIdx.x;
  const int lane = tid & 63, wave = tid >> 6;
  const int r = lane >> 4, t = lane & 15;
  const int row = blockIdx.x * 16 + wave * 4 + r;

  for (int e = tid; e < ED * NT; e += 256) {
    int d = e >> 4, tt = e & 15;
    wt[tt * WSTR + d] = W[e];
  }

  const int tok = text[row];
  const float4* erow = (const float4*)(emb + (size_t)tok * ED);
  float acc = bias[t];

  float4 A[8];
#pragma unroll
  for (int i = 0; i < 8; ++i) A[i] = erow[i];

  __syncthreads();

  const float4* w4 = (const float4*)(wt + t * WSTR);
#pragma unroll
  for (int c = 0; c < 75; ++c) {
    float4 e = A[c & 7];
    if (c < 67) A[c & 7] = erow[c + 8];
    float4 w = w4[c];
    acc = fmaf(e.x, w.x, acc);
    acc = fmaf(e.y, w.y, acc);
    acc = fmaf(e.z, w.z, acc);
    acc = fmaf(e.w, w.w, acc);
  }
  out_probs[(size_t)row * NT + t] = acc;
}

// ---------------------------------------------------------------------------
// DPP helpers (controls HW-verified rounds 1-6). old = src (involutions, all
// lanes active -> old never observed).
// ---------------------------------------------------------------------------
template <int CTRL>
__device__ __forceinline__ float dppmov(float x) {
  int xi = __float_as_int(x);
  return __int_as_float(
      __builtin_amdgcn_update_dpp(xi, xi, CTRL, 0xF, 0xF, false));
}

// ---------------------------------------------------------------------------
// One CRF forward step, fused DPP matvec (HW-verified rounds 3-6).
//   gn_j = (sum_k alpha_{j^k} * E[k]_j) * pe_j,  E[k]_j ~ exp(trans[j^k, j])
// ---------------------------------------------------------------------------
__device__ __forceinline__ float crf_step(float g, float pe, const float E[16]) {
  float gn, h, m, c, a1, a2, a3;
  asm("s_nop 1\n\t"
      "v_mov_b32_dpp %[h], %[g] row_half_mirror row_mask:0xf bank_mask:0xf\n\t"
      "v_mov_b32_dpp %[m], %[g] row_mirror row_mask:0xf bank_mask:0xf\n\t"
      "v_mul_f32 %[gn], %[g], %[e0]\n\t"
      "v_fmac_f32_dpp %[gn], %[g], %[e1] quad_perm:[1,0,3,2] row_mask:0xf bank_mask:0xf\n\t"
      "v_fmac_f32_dpp %[gn], %[g], %[e2] quad_perm:[2,3,0,1] row_mask:0xf bank_mask:0xf\n\t"
      "v_fmac_f32_dpp %[gn], %[g], %[e3] quad_perm:[3,2,1,0] row_mask:0xf bank_mask:0xf\n\t"
      "v_mov_b32_dpp %[c], %[m] row_half_mirror row_mask:0xf bank_mask:0xf\n\t"
      "v_mul_f32 %[a1], %[h], %[e7]\n\t"
      "v_fmac_f32_dpp %[a1], %[h], %[e6] quad_perm:[1,0,3,2] row_mask:0xf bank_mask:0xf\n\t"
      "v_fmac_f32_dpp %[a1], %[h], %[e5] quad_perm:[2,3,0,1] row_mask:0xf bank_mask:0xf\n\t"
      "v_fmac_f32_dpp %[a1], %[h], %[e4] quad_perm:[3,2,1,0] row_mask:0xf bank_mask:0xf\n\t"
      "v_mul_f32 %[a2], %[m], %[e15]\n\t"
      "v_fmac_f32_dpp %[a2], %[m], %[e14] quad_perm:[1,0,3,2] row_mask:0xf bank_mask:0xf\n\t"
      "v_fmac_f32_dpp %[a2], %[m], %[e13] quad_perm:[2,3,0,1] row_mask:0xf bank_mask:0xf\n\t"
      "v_fmac_f32_dpp %[a2], %[m], %[e12] quad_perm:[3,2,1,0] row_mask:0xf bank_mask:0xf\n\t"
      "v_mul_f32 %[a3], %[c], %[e8]\n\t"
      "v_fmac_f32_dpp %[a3], %[c], %[e9] quad_perm:[1,0,3,2] row_mask:0xf bank_mask:0xf\n\t"
      "v_fmac_f32_dpp %[a3], %[c], %[e10] quad_perm:[2,3,0,1] row_mask:0xf bank_mask:0xf\n\t"
      "v_fmac_f32_dpp %[a3], %[c], %[e11] quad_perm:[3,2,1,0] row_mask:0xf bank_mask:0xf\n\t"
      "v_add_f32 %[gn], %[gn], %[a1]\n\t"
      "v_add_f32 %[a2], %[a2], %[a3]\n\t"
      "v_add_f32 %[gn], %[gn], %[a2]\n\t"
      "v_mul_f32 %[gn], %[gn], %[pe]"
      : [gn] "=&v"(gn), [h] "=&v"(h), [m] "=&v"(m), [c] "=&v"(c),
        [a1] "=&v"(a1), [a2] "=&v"(a2), [a3] "=&v"(a3)
      : [g] "v"(g), [pe] "v"(pe),
        [e0] "v"(E[0]), [e1] "v"(E[1]), [e2] "v"(E[2]), [e3] "v"(E[3]),
        [e4] "v"(E[4]), [e5] "v"(E[5]), [e6] "v"(E[6]), [e7] "v"(E[7]),
        [e8] "v"(E[8]), [e9] "v"(E[9]), [e10] "v"(E[10]), [e11] "v"(E[11]),
        [e12] "v"(E[12]), [e13] "v"(E[13]), [e14] "v"(E[14]), [e15] "v"(E[15]));
  return gn;
}

// ---------------------------------------------------------------------------
// Kernel 2: lens + CRF log-likelihood (round-4 structure). One batch/block,
// 64 threads. Scan in scaled-linear space; E pre-scaled by 2^-5 so per-step
// growth ~1 -> renorm only every 4 chunks (64 steps). The analytic scale
// 5*T is added back to K2 at the end. Steps s>=len are exact no-ops: skipped
// via dynamic trip count.
// ---------------------------------------------------------------------------
__global__ __launch_bounds__(64) void crf_kernel(const int* __restrict__ text,
                                                 const int* __restrict__ tags,
                                                 const float* __restrict__ trans,
                                                 const float* __restrict__ probs,
                                                 float* __restrict__ out_lens,
                                                 float* __restrict__ out_ll) {
  __shared__ float lps[(SS + 1) * NT];  // probs * LOG2E, +1 pad row
  __shared__ int tgs[SS];
  __shared__ float trs[256];

  const int tid = threadIdx.x;
  const int j = tid & 15;
  const int b = blockIdx.x;

  // ---- stage (coalesced), pre-scaling probs by log2e ----
  {
    const float4* p4 = (const float4*)(probs + (size_t)b * SS * NT);
    float4* l4 = (float4*)lps;
#pragma unroll
    for (int i = 0; i < 32; ++i) {
      float4 v = p4[tid + 64 * i];
      v.x *= LOG2E; v.y *= LOG2E; v.z *= LOG2E; v.w *= LOG2E;
      l4[tid + 64 * i] = v;
    }
    const int4* t4 = (const int4*)(tags + b * SS);
    int4* lt = (int4*)tgs;
#pragma unroll
    for (int i = 0; i < 2; ++i) lt[tid + 64 * i] = t4[tid + 64 * i];
    for (int i = tid; i < 256; i += 64) trs[i] = trans[i];
  }
  __syncthreads();

  // ---- lens (fused) ----
  const int* tx = text + b * SS;
  int cnt = 0;
#pragma unroll
  for (int k = 0; k < 8; ++k) cnt += (tx[tid + 64 * k] != 0) ? 1 : 0;
  for (int off = 32; off > 0; off >>= 1) cnt += __shfl_xor(cnt, off, 64);
  const int len = cnt;
  if (tid == 0) out_lens[b] = (float)len;

  // ---- phase A: unary + binary scores ----
  float su = 0.f, sb = 0.f;
#pragma unroll
  for (int it = 0; it < 8; ++it) {
    const int s = tid + 64 * it;
    if (s < len) {
      int t1 = tgs[s];
      su += lps[s * NT + t1];
      if (s >= 1) sb += trs[tgs[s - 1] * 16 + t1];
    }
  }
  float sc = fmaf(su, LN2, sb);
  for (int off = 32; off > 0; off >>= 1) sc += __shfl_xor(sc, off, 64);

  // ---- E[k] = exp(trans[j^k, j]) * 2^-5 (scale folded back via K2) ----
  float E[16];
#pragma unroll
  for (int k = 0; k < 16; ++k) E[k] = __expf(trs[((j ^ k) << 4) + j]) * 0.03125f;

  // ---- scan: s = 1 .. len-1 ----
  float g = exp2f(lps[j]);  // alpha from step 0
  float K2 = 0.f;

  const int T = (len > 0) ? len - 1 : 0;
  const int nfull = T >> 4;
  const int rem = T & 15;

  float raw[16];
#pragma unroll
  for (int c = 0; c < 16; ++c) raw[c] = lps[(1 + c) * NT + j];

  int s0 = 1;
  for (int blk = 0; blk < nfull; ++blk) {
#pragma unroll
    for (int c = 0; c < 16; ++c) {
      float pe = exp2f(raw[c]);
      raw[c] = lps[(s0 + 16 + c) * NT + j];  // rows <= 512 (pad row)
      g = crf_step(g, pe, E);
    }
    // renorm every 4 chunks = 64 steps. Per-step factor in [~0.4, ~1.8]
    // (E scaled to ~1/16-th of row-sum), so worst 79-step span stays within
    // 2^+-90 < fp32 range. Exact fold into K2.
    if ((blk & 3) == 3) {
      float mx = g;
      mx = fmaxf(mx, dppmov<0xB1>(mx));
      mx = fmaxf(mx, dppmov<0x4E>(mx));
      mx = fmaxf(mx, dppmov<0x141>(mx));
      mx = fmaxf(mx, dppmov<0x140>(mx));
      float rr = 1.0f / mx;
      K2 -= __log2f(rr);
      g *= rr;
    }
    s0 += 16;
  }
  for (int c = 0; c < rem; ++c) {
    float pe = exp2f(raw[c]);
    g = crf_step(g, pe, E);
  }

  // ---- final logsumexp across the 16 alphas; +5*T undoes the E scaling ----
  float x = g;
  x += dppmov<0xB1>(x);
  x += dppmov<0x4E>(x);
  x += dppmov<0x141>(x);
  x += dppmov<0x140>(x);
  float log_norm = LN2 * (K2 + 5.0f * (float)T + __log2f(x));
  if (tid == 0) out_ll[b] = sc - log_norm;
}

// ---------------------------------------------------------------------------
extern "C" void kernel_launch(void* const* d_in, const int* in_sizes, int n_in,
                              void* d_out, int out_size, void* d_ws, size_t ws_size,
                              hipStream_t stream) {
  const int* text = (const int*)d_in[0];
  const int* tags = (const int*)d_in[1];
  const float* emb = (const float*)d_in[2];
  const float* W = (const float*)d_in[3];
  const float* bias = (const float*)d_in[4];
  const float* trans = (const float*)d_in[5];

  float* out = (float*)d_out;
  float* out_probs = out;                   // 64*512*16
  float* out_lens = out + BB * SS * NT;     // 64
  float* out_ll = out + BB * SS * NT + BB;  // 64

  probs_kernel<<<(BB * SS) / 16, 256, 0, stream>>>(text, emb, W, bias, out_probs);
  crf_kernel<<<BB, 64, 0, stream>>>(text, tags, trans, out_probs, out_lens, out_ll);
}